// Round 2
// baseline (111.932 us; speedup 1.0000x reference)
//
#include <hip/hip_runtime.h>
#include <math.h>

// tanh(delta^T M delta) for pairs of 20 amino-acid feature rows.
// idx in [0,20) => only 400 distinct outputs. Precompute table, then gather.

constexpr int NUM_AA = 20;
constexpr int FEAT   = 16;
constexpr int TABLE  = NUM_AA * NUM_AA; // 400

// Native clang vectors — required by __builtin_nontemporal_store (the HIP
// float4/int4 classes are rejected: "must be ... or a vector of such types").
typedef float fv4 __attribute__((ext_vector_type(4)));
typedef int   iv4 __attribute__((ext_vector_type(4)));

// ---------------- Kernel A: build the 400-entry lookup table ----------------
__global__ __launch_bounds__(512) void build_table(
    const float* __restrict__ F,   // [20,16]
    const float* __restrict__ M,   // [16,16]
    float* __restrict__ tab)       // [400] out (in d_ws)
{
    __shared__ float sF[NUM_AA * FEAT]; // 320 floats
    __shared__ float sM[FEAT * FEAT];   // 256 floats
    const int t = threadIdx.x;
    for (int k = t; k < NUM_AA * FEAT; k += 512) sF[k] = F[k];
    for (int k = t; k < FEAT * FEAT; k += 512)   sM[k] = M[k];
    __syncthreads();

    if (t < TABLE) {
        const int i = t / NUM_AA;
        const int j = t - i * NUM_AA;
        float delta[FEAT];
#pragma unroll
        for (int d = 0; d < FEAT; ++d)
            delta[d] = sF[i * FEAT + d] - sF[j * FEAT + d];
        float dist = 0.f;
#pragma unroll
        for (int d = 0; d < FEAT; ++d) {
            float md = 0.f;
#pragma unroll
            for (int e = 0; e < FEAT; ++e)
                md = fmaf(sM[d * FEAT + e], delta[e], md);
            dist = fmaf(delta[d], md, dist);
        }
        tab[t] = tanhf(dist);
    }
}

// ------- Kernel B: persistent grid-stride gather through LDS table ----------
// 2048 blocks (8/CU -> full 32-wave occupancy). Table staged ONCE per block,
// then each thread handles nvec/(2048*256) vec4 chunks (4 at P=8M) with a
// 2-deep unroll for memory-level parallelism. Nontemporal stores keep the
// index streams resident in L2/L3.
__global__ __launch_bounds__(256) void gather_pairs(
    const float* __restrict__ tab,      // [400] in d_ws
    const iv4* __restrict__ ii4,        // idx_i as int4
    const iv4* __restrict__ jj4,        // idx_j as int4
    fv4* __restrict__ out4,             // output as float4
    int nvec,                           // P/4
    const int* __restrict__ ii_s,       // scalar views for tail
    const int* __restrict__ jj_s,
    float* __restrict__ out_s,
    int tail_start, int total)          // tail handling (P % 4)
{
    __shared__ float s[TABLE]; // 1.6 KB
    for (int k = threadIdx.x; k < TABLE; k += 256) s[k] = tab[k];
    __syncthreads();

    const int T = (int)gridDim.x * 256;
    int v = blockIdx.x * 256 + threadIdx.x;

    // 2-deep unrolled grid-stride loop: 4 independent index loads in flight.
    for (; v + T < nvec; v += 2 * T) {
        const iv4 iA = ii4[v];
        const iv4 jA = jj4[v];
        const iv4 iB = ii4[v + T];
        const iv4 jB = jj4[v + T];
        fv4 oA, oB;
        oA.x = s[iA.x * NUM_AA + jA.x];
        oA.y = s[iA.y * NUM_AA + jA.y];
        oA.z = s[iA.z * NUM_AA + jA.z];
        oA.w = s[iA.w * NUM_AA + jA.w];
        oB.x = s[iB.x * NUM_AA + jB.x];
        oB.y = s[iB.y * NUM_AA + jB.y];
        oB.z = s[iB.z * NUM_AA + jB.z];
        oB.w = s[iB.w * NUM_AA + jB.w];
        __builtin_nontemporal_store(oA, &out4[v]);
        __builtin_nontemporal_store(oB, &out4[v + T]);
    }
    for (; v < nvec; v += T) {
        const iv4 iA = ii4[v];
        const iv4 jA = jj4[v];
        fv4 oA;
        oA.x = s[iA.x * NUM_AA + jA.x];
        oA.y = s[iA.y * NUM_AA + jA.y];
        oA.z = s[iA.z * NUM_AA + jA.z];
        oA.w = s[iA.w * NUM_AA + jA.w];
        __builtin_nontemporal_store(oA, &out4[v]);
    }

    // tail (P % 4 != 0) — block 0 handles up to 3 scalars
    if (blockIdx.x == 0) {
        const int p = tail_start + (int)threadIdx.x;
        if (p < total)
            out_s[p] = s[ii_s[p] * NUM_AA + jj_s[p]];
    }
}

extern "C" void kernel_launch(void* const* d_in, const int* in_sizes, int n_in,
                              void* d_out, int out_size, void* d_ws, size_t ws_size,
                              hipStream_t stream)
{
    const float* F   = (const float*)d_in[0];
    const float* M   = (const float*)d_in[1];
    const int*   ii  = (const int*)d_in[2];
    const int*   jj  = (const int*)d_in[3];
    float*       out = (float*)d_out;
    float*       tab = (float*)d_ws;   // 400 floats = 1.6 KB scratch

    const int P    = in_sizes[2];
    const int nvec = P >> 2;           // 2,097,152 for P = 8,388,608
    const int tail = nvec << 2;        // first scalar index of tail (== P here)

    build_table<<<1, 512, 0, stream>>>(F, M, tab);

    int blocks = (nvec + 255) / 256;
    if (blocks > 2048) blocks = 2048;  // persistent: 8 blocks/CU, grid-stride
    if (blocks < 1)    blocks = 1;
    gather_pairs<<<blocks, 256, 0, stream>>>(
        tab, (const iv4*)ii, (const iv4*)jj, (fv4*)out,
        nvec, ii, jj, out, tail, P);
}